// Round 20
// baseline (137.865 us; speedup 1.0000x reference)
//
#include <hip/hip_runtime.h>

typedef short bf16x8 __attribute__((ext_vector_type(8)));
typedef float f32x4 __attribute__((ext_vector_type(4)));
typedef float f32x16 __attribute__((ext_vector_type(16)));

#define AS1 __attribute__((address_space(1)))
#define AS3 __attribute__((address_space(3)))

__device__ __forceinline__ void gload16(const void* g, void* l) {
  __builtin_amdgcn_global_load_lds((const AS1 void*)g, (AS3 void*)l, 16, 0, 0);
}

__device__ __forceinline__ unsigned short f2bf(float f) {
  union { float f; unsigned u; } v; v.f = f;
  unsigned r = v.u + 0x7FFFu + ((v.u >> 16) & 1u);
  return (unsigned short)(r >> 16);
}

// packed f32x2 -> bf16x2 (low = a, high = b), RNE
__device__ __forceinline__ unsigned cvtpk(float a, float b) {
  unsigned r;
  asm("v_cvt_pk_bf16_f32 %0, %1, %2" : "=v"(r) : "v"(a), "v"(b));
  return r;
}
// TRUE semantics: after plswap(X,Y): X=(X_lo,Y_lo), Y=(X_hi,Y_hi) (halves = lane<32 / >=32).
// ONLY safe with DISTINCT registers (rounds 3-8 forensics: xx==yy aliases degenerate).
__device__ __forceinline__ void plswap(unsigned& d, unsigned& s) {
  asm("v_permlane32_swap_b32 %0, %1" : "+v"(d), "+v"(s));
}

// NOTE (r14): grid fixed at 768 attn blocks -> never shrink block size.
// NOTE (r15): attn staging depth not binding; serial chain was (fixed by T15 in r16).
// NOTE (r17): GEMM in-block dbuf regressed (64KB LDS halved blocks/CU; TLP is the hider).
// NOTE (r18): swapped epilogue regressed (8B stores at 128B token-stride uncoalesced).
// NOTE (r19): BM=64 flat despite occupancy 35% -> limiter is LDS bytes per MFMA.
//             Fix: bigger per-wave tile (64x128 acc: 12 ds_reads feed 64 MFMAs/K-step).

// ---------------- merged cast fp32 -> bf16 (x, qkv_w, proj_w in one launch) ----------------
__global__ __launch_bounds__(256) void cast_all(
    const float* __restrict__ x, const float* __restrict__ w1, const float* __restrict__ w2,
    unsigned short* __restrict__ xb, unsigned short* __restrict__ w1b,
    unsigned short* __restrict__ w2b) {
  int i = blockIdx.x * blockDim.x + threadIdx.x;
  const float* in; unsigned short* out;
  if (i < 1572864) { in = x; out = xb; }
  else if (i < 2015232) { i -= 1572864; in = w1; out = w1b; }
  else { i -= 2015232; in = w2; out = w2b; }
  float4 v = reinterpret_cast<const float4*>(in)[i];
  ushort4 o; o.x = f2bf(v.x); o.y = f2bf(v.y); o.z = f2bf(v.z); o.w = f2bf(v.w);
  reinterpret_cast<ushort4*>(out)[i] = o;
}

// ---------------- tiled GEMM, BK=64, swizzled LDS (r16 loop/epilogue formulas) ---------------
// MODE 0: QKV gemm, BM=128 x BN=256 (4 waves x 64x128 acc -> 64 MFMA per 12 ds_reads),
//         grid 576, head-packed Q/K [bh][n][64] (Q pre-scaled by c1), V^T [bh][64][n].
// MODE 1: proj gemm, BM=64 x BN=128 (r19-verified), fp32 out + bias, grid 768.
// 1D grid + T1 XCD-chunked bijective swizzle (nwg divisible by 8 in both modes).
template<int MODE>
__global__ __launch_bounds__(256) void gemm128(
    const unsigned short* __restrict__ A, const unsigned short* __restrict__ B,
    int K, int N,
    unsigned short* __restrict__ Qh, unsigned short* __restrict__ Kh,
    unsigned short* __restrict__ Vt,
    float* __restrict__ Cf, const float* __restrict__ bias) {
  constexpr int BM = (MODE == 0) ? 128 : 64;
  constexpr int BN = (MODE == 0) ? 256 : 128;
  constexpr int MREP = BM / 32;                 // 4 / 2
  constexpr int NREP = BN / 32;                 // 8 / 4
  constexpr int NX = (MODE == 0) ? 9 : 6;       // blocks along N
  constexpr int CPX = (MODE == 0) ? 72 : 96;    // blocks per XCD chunk (nwg/8)
  __shared__ unsigned short Ab[BM * 64];        // 16 KB / 8 KB
  __shared__ unsigned short Bb[BN * 64];        // 32 KB / 16 KB
  const int tid = threadIdx.x, lane = tid & 63, wave = tid >> 6;
  const int l15 = lane & 15, lhi = lane >> 4;
  const int bid = blockIdx.x;
  const int s = (bid & 7) * CPX + (bid >> 3);   // bijective XCD-chunked remap
  const int m0 = (s / NX) * BM, n0 = (s % NX) * BN;
  const int wr = wave >> 1, wc = wave & 1;

  f32x4 acc[MREP][NREP] = {};

  const int srow = tid >> 3;
  const int scol = (((tid & 7) * 16) ^ ((srow & 7) << 4)) >> 1;
  const unsigned short* aSrc = A + (size_t)(m0 + srow) * K + scol;
  const unsigned short* bSrc = B + (size_t)(n0 + srow) * K + scol;
  char* ldsA = (char*)Ab + wave * 1024;
  char* ldsB = (char*)Bb + wave * 1024;

  const int rswz = (l15 & 7) << 4;

  for (int k0 = 0; k0 < K; k0 += 64) {
    __syncthreads();
#pragma unroll
    for (int i = 0; i < BM / 32; ++i)
      gload16(aSrc + k0 + (size_t)32 * K * i, ldsA + i * 4096);
#pragma unroll
    for (int i = 0; i < BN / 32; ++i)
      gload16(bSrc + k0 + (size_t)32 * K * i, ldsB + i * 4096);
    __syncthreads();
#pragma unroll
    for (int ks = 0; ks < 2; ++ks) {
      bf16x8 af[MREP], bfr[NREP];
#pragma unroll
      for (int mm = 0; mm < MREP; ++mm)
        af[mm] = *reinterpret_cast<const bf16x8*>(
            (char*)Ab + (wr * (BM / 2) + mm * 16 + l15) * 128 + ((ks * 64 + lhi * 16) ^ rswz));
#pragma unroll
      for (int nn = 0; nn < NREP; ++nn)
        bfr[nn] = *reinterpret_cast<const bf16x8*>(
            (char*)Bb + (wc * (BN / 2) + nn * 16 + l15) * 128 + ((ks * 64 + lhi * 16) ^ rswz));
#pragma unroll
      for (int mm = 0; mm < MREP; ++mm)
#pragma unroll
        for (int nn = 0; nn < NREP; ++nn)
          acc[mm][nn] = __builtin_amdgcn_mfma_f32_16x16x32_bf16(af[mm], bfr[nn], acc[mm][nn], 0, 0, 0);
    }
  }

  if (MODE == 0) {
    // BN=256 divides 768 -> region constant per block
    const int region = (n0 >= 1536) ? 2 : (n0 >= 768 ? 1 : 0);
    const float qs = (region == 0) ? 0.125f * 1.44269504088896340736f : 1.f;
#pragma unroll
    for (int mm = 0; mm < MREP; ++mm) {
      int gm = m0 + wr * (BM / 2) + mm * 16 + lhi * 4;
      int bb = gm >> 10, nb = gm & 1023;
#pragma unroll
      for (int nn = 0; nn < NREP; ++nn) {
        int gn = n0 + wc * (BN / 2) + nn * 16 + l15 - region * 768;
        int d = gn & 63, hh = gn >> 6;
        if (region == 2) {
          ushort4 o;
          o.x = f2bf(acc[mm][nn][0]); o.y = f2bf(acc[mm][nn][1]);
          o.z = f2bf(acc[mm][nn][2]); o.w = f2bf(acc[mm][nn][3]);
          *reinterpret_cast<ushort4*>(&Vt[((size_t)(bb * 12 + hh) * 64 + d) * 1024 + nb]) = o;
        } else {
          unsigned short* dst =
              (region == 0 ? Qh : Kh) + ((size_t)(bb * 12 + hh) * 1024 + nb) * 64 + d;
#pragma unroll
          for (int r = 0; r < 4; ++r) dst[(size_t)r * 64] = f2bf(acc[mm][nn][r] * qs);
        }
      }
    }
  } else {
#pragma unroll
    for (int mm = 0; mm < MREP; ++mm) {
      int gm = m0 + wr * (BM / 2) + mm * 16 + lhi * 4;
#pragma unroll
      for (int nn = 0; nn < NREP; ++nn) {
        int gn = n0 + wc * (BN / 2) + nn * 16 + l15;
        float bv = bias[gn];
#pragma unroll
        for (int r = 0; r < 4; ++r)
          Cf[(size_t)(gm + r) * N + gn] = acc[mm][nn][r] + bv;
      }
    }
  }
}

// ---------------- flash attention: r16 verified (T15 2-state pipeline, 3-deep staging) --------
__global__ __launch_bounds__(256) void attn_kernel(
    const unsigned short* __restrict__ qh, const unsigned short* __restrict__ kh,
    const unsigned short* __restrict__ vt, unsigned short* __restrict__ aout) {
  __shared__ unsigned short KT[3][4096];  // [kv 64][d 64] swizzled, 8KB/buf
  __shared__ unsigned short VT[3][4096];  // [d 64][kv 64] swizzled, 8KB/buf

  const int tid = threadIdx.x, lane = tid & 63, wave = tid >> 6;
  const int l31 = lane & 31, hi = lane >> 5;
  // XCD-locality: all 8 q-tiles of one bh on one XCD (96 % 8 == 0)
  const int bh = blockIdx.x % 96, qt = blockIdx.x / 96;
  const int b = bh / 12, h = bh % 12;

  // staging: thread t -> tile row t>>3 (+32), chunk t&7, inverse-swizzled src col
  const int srow = tid >> 3;
  const int scol = (((tid & 7) * 16) ^ ((srow & 7) << 4)) >> 1;
  const unsigned short* kS0 = kh + ((size_t)bh * 1024 + srow) * 64 + scol;
  const unsigned short* kS1 = kS0 + (size_t)32 * 64;
  const unsigned short* vS0 = vt + ((size_t)bh * 64 + srow) * 1024 + scol;
  const unsigned short* vS1 = vS0 + (size_t)32 * 1024;
  char* kDb = (char*)&KT[0][0] + wave * 1024;
  char* vDb = (char*)&VT[0][0] + wave * 1024;

  // Q as B-operand (col=q=l31, k=hi*8+j), 4 k-slices of 16
  const int qw0 = qt * 128 + wave * 32;
  const unsigned short* qbase = qh + ((size_t)bh * 1024 + qw0 + l31) * 64 + hi * 8;
  bf16x8 qf[4];
#pragma unroll
  for (int ks = 0; ks < 4; ++ks)
    qf[ks] = *reinterpret_cast<const bf16x8*>(qbase + ks * 16);

  f32x16 oacc[2] = {};
  float lsum = 0.f;

  const int swz = (l31 & 7) << 4;
  const int rowb = l31 * 128;

  // PV B-frag from 8 exp'd values (verified r12-r19)
  auto mkfrag = [&](const f32x16& e, int s8) -> bf16x8 {
    unsigned A0 = cvtpk(e[s8 + 0], e[s8 + 1]);
    unsigned A1 = cvtpk(e[s8 + 2], e[s8 + 3]);
    unsigned B0 = cvtpk(e[s8 + 4], e[s8 + 5]);
    unsigned B1 = cvtpk(e[s8 + 6], e[s8 + 7]);
    plswap(A0, B0);
    plswap(A1, B1);
    union { unsigned u[4]; bf16x8 v; } wu;
    wu.u[0] = A0; wu.u[1] = A1; wu.u[2] = B0; wu.u[3] = B1;
    return wu.v;
  };

  auto qkt = [&](const char* kb, f32x16& r0, f32x16& r1) {
    __builtin_amdgcn_s_setprio(1);
#pragma unroll
    for (int ks = 0; ks < 4; ++ks) {
      bf16x8 k0 = *reinterpret_cast<const bf16x8*>(kb + rowb + ((ks * 32 + hi * 16) ^ swz));
      bf16x8 k1 = *reinterpret_cast<const bf16x8*>(kb + 4096 + rowb + ((ks * 32 + hi * 16) ^ swz));
      r0 = __builtin_amdgcn_mfma_f32_32x32x16_bf16(k0, qf[ks], r0, 0, 0, 0);
      r1 = __builtin_amdgcn_mfma_f32_32x32x16_bf16(k1, qf[ks], r1, 0, 0, 0);
    }
    __builtin_amdgcn_s_setprio(0);
  };

  // prologue: stage tiles 0,1; wait own tile 0 (vmcnt(4): tile1 stays in flight); QK(0)
#pragma unroll
  for (int t = 0; t < 2; ++t) {
    const int kv = t * 64;
    char* kd = kDb + t * 8192;
    char* vd = vDb + t * 8192;
    gload16(kS0 + (size_t)kv * 64, kd); gload16(kS1 + (size_t)kv * 64, kd + 4096);
    gload16(vS0 + kv, vd); gload16(vS1 + kv, vd + 4096);
  }
  asm volatile("s_waitcnt vmcnt(4)" ::: "memory");
  __builtin_amdgcn_s_barrier();
  f32x16 pn0 = {}, pn1 = {};
  qkt((const char*)&KT[0][0], pn0, pn1);

  for (int kt = 0; kt < 16; ++kt) {
    const int cur = kt % 3;
    asm volatile("s_waitcnt vmcnt(0)" ::: "memory");
    __builtin_amdgcn_s_barrier();
    if (kt + 2 <= 15) {  // stage kt+2 into buf (kt+2)%3
      const int kv = (kt + 2) * 64;
      const int nb = (kt + 2) % 3;
      char* kd = kDb + nb * 8192;
      char* vd = vDb + nb * 8192;
      gload16(kS0 + (size_t)kv * 64, kd); gload16(kS1 + (size_t)kv * 64, kd + 4096);
      gload16(vS0 + kv, vd); gload16(vS1 + kv, vd + 4096);
    }

    // take current P from pipeline; issue NEXT tile's QK^T (MFMA fills while softmax VALU runs)
    f32x16 p0 = pn0, p1 = pn1;
    if (kt < 15) {
      pn0 = f32x16{}; pn1 = f32x16{};
      qkt((const char*)&KT[(kt + 1) % 3][0], pn0, pn1);
    }

    // shift-free softmax numerator: P = exp2(S'), running sum (verified r13)
#pragma unroll
    for (int i = 0; i < 16; ++i) {
      p0[i] = __builtin_amdgcn_exp2f(p0[i]);
      p1[i] = __builtin_amdgcn_exp2f(p1[i]);
    }
    float su[8];
#pragma unroll
    for (int i = 0; i < 8; ++i)
      su[i] = (p0[i] + p0[i + 8]) + (p1[i] + p1[i + 8]);
    float s4[4];
#pragma unroll
    for (int i = 0; i < 4; ++i) s4[i] = su[i] + su[i + 4];
    lsum += (s4[0] + s4[1]) + (s4[2] + s4[3]);

    // P -> bf16 PV B-frags in-register (T12)
    bf16x8 pb[4];
    pb[0] = mkfrag(p0, 0); pb[1] = mkfrag(p0, 8);
    pb[2] = mkfrag(p1, 0); pb[3] = mkfrag(p1, 8);

    // PV swapped: O^T[d][q] += V^T x P (reads buf kt%3)
    const char* vb = (const char*)&VT[cur][0];
    __builtin_amdgcn_s_setprio(1);
#pragma unroll
    for (int kseg = 0; kseg < 4; ++kseg) {
      bf16x8 v0 = *reinterpret_cast<const bf16x8*>(vb + rowb + ((kseg * 32 + hi * 16) ^ swz));
      bf16x8 v1 = *reinterpret_cast<const bf16x8*>(vb + 4096 + rowb + ((kseg * 32 + hi * 16) ^ swz));
      oacc[0] = __builtin_amdgcn_mfma_f32_32x32x16_bf16(v0, pb[kseg], oacc[0], 0, 0, 0);
      oacc[1] = __builtin_amdgcn_mfma_f32_32x32x16_bf16(v1, pb[kseg], oacc[1], 0, 0, 0);
    }
    __builtin_amdgcn_s_setprio(0);
  }

  // epilogue: combine halves, normalize, write
  lsum += __shfl_xor(lsum, 32, 64);
  float inv = 1.f / lsum;
#pragma unroll
  for (int dblk = 0; dblk < 2; ++dblk)
#pragma unroll
    for (int g = 0; g < 4; ++g) {
      ushort4 o;
      o.x = f2bf(oacc[dblk][4 * g + 0] * inv);
      o.y = f2bf(oacc[dblk][4 * g + 1] * inv);
      o.z = f2bf(oacc[dblk][4 * g + 2] * inv);
      o.w = f2bf(oacc[dblk][4 * g + 3] * inv);
      int d = dblk * 32 + 8 * g + 4 * hi;  // row=(reg&3)+8*(reg>>2)+4*hi (m74)
      *reinterpret_cast<ushort4*>(
          aout + ((size_t)(b * 1024 + qw0 + l31)) * 768 + h * 64 + d) = o;
    }
}

extern "C" void kernel_launch(void* const* d_in, const int* in_sizes, int n_in,
                              void* d_out, int out_size, void* d_ws, size_t ws_size,
                              hipStream_t stream) {
  const float* x      = (const float*)d_in[0];
  const float* qkv_w  = (const float*)d_in[1];
  const float* proj_w = (const float*)d_in[2];
  const float* proj_b = (const float*)d_in[3];
  float* out = (float*)d_out;

  char* ws = (char*)d_ws;
  unsigned short* xb     = (unsigned short*)(ws);              // 8192x768 bf16
  unsigned short* wqkvb  = (unsigned short*)(ws + 12582912);   // 2304x768
  unsigned short* wprojb = (unsigned short*)(ws + 16121856);   // 768x768
  unsigned short* qhb    = (unsigned short*)(ws + 17301504);   // [96][1024][64]
  unsigned short* khb    = (unsigned short*)(ws + 29884416);   // [96][1024][64]
  unsigned short* vtb    = (unsigned short*)(ws + 42467328);   // [96][64][1024]
  unsigned short* aob    = (unsigned short*)(ws + 55050240);   // 8192x768

  cast_all<<<8448, 256, 0, stream>>>(x, qkv_w, proj_w, xb, wqkvb, wprojb);

  gemm128<0><<<576, 256, 0, stream>>>(xb, wqkvb, 768, 2304, qhb, khb, vtb, nullptr, nullptr);

  attn_kernel<<<96 * 8, 256, 0, stream>>>(qhb, khb, vtb, aob);

  gemm128<1><<<768, 256, 0, stream>>>(aob, wprojb, 768, 768, nullptr, nullptr, nullptr, out, proj_b);
}

// Round 21
// 105.244 us; speedup vs baseline: 1.3100x; 1.3100x over previous
//
#include <hip/hip_runtime.h>

typedef short bf16x8 __attribute__((ext_vector_type(8)));
typedef float f32x4 __attribute__((ext_vector_type(4)));
typedef float f32x16 __attribute__((ext_vector_type(16)));

#define AS1 __attribute__((address_space(1)))
#define AS3 __attribute__((address_space(3)))

__device__ __forceinline__ void gload16(const void* g, void* l) {
  __builtin_amdgcn_global_load_lds((const AS1 void*)g, (AS3 void*)l, 16, 0, 0);
}

__device__ __forceinline__ unsigned short f2bf(float f) {
  union { float f; unsigned u; } v; v.f = f;
  unsigned r = v.u + 0x7FFFu + ((v.u >> 16) & 1u);
  return (unsigned short)(r >> 16);
}

// packed f32x2 -> bf16x2 (low = a, high = b), RNE
__device__ __forceinline__ unsigned cvtpk(float a, float b) {
  unsigned r;
  asm("v_cvt_pk_bf16_f32 %0, %1, %2" : "=v"(r) : "v"(a), "v"(b));
  return r;
}
// TRUE semantics: after plswap(X,Y): X=(X_lo,Y_lo), Y=(X_hi,Y_hi) (halves = lane<32 / >=32).
// ONLY safe with DISTINCT registers (rounds 3-8 forensics: xx==yy aliases degenerate).
__device__ __forceinline__ void plswap(unsigned& d, unsigned& s) {
  asm("v_permlane32_swap_b32 %0, %1" : "+v"(d), "+v"(s));
}

// NOTE (r14): grid fixed at 768 attn blocks -> never shrink block size.
// NOTE (r17/r20): GEMM bigger tiles / in-block dbuf regress via occupancy; TLP is the hider.
//                 gemm1 = 45us is the 2-barrier structure's shape limit; r16 config is final.
// NOTE (r18): swapped epilogue regressed (uncoalesced 8B token-stride stores).
// NOTE (r21): attn 3-buf (48KB) capped at 3 blocks/CU; 2-buf split-K/V staging with
//             counted vmcnt(2) keeps the T15 pipeline at 5 blocks/CU.

// ---------------- merged cast fp32 -> bf16 (x, qkv_w, proj_w in one launch) ----------------
__global__ __launch_bounds__(256) void cast_all(
    const float* __restrict__ x, const float* __restrict__ w1, const float* __restrict__ w2,
    unsigned short* __restrict__ xb, unsigned short* __restrict__ w1b,
    unsigned short* __restrict__ w2b) {
  int i = blockIdx.x * blockDim.x + threadIdx.x;
  const float* in; unsigned short* out;
  if (i < 1572864) { in = x; out = xb; }
  else if (i < 2015232) { i -= 1572864; in = w1; out = w1b; }
  else { i -= 2015232; in = w2; out = w2b; }
  float4 v = reinterpret_cast<const float4*>(in)[i];
  ushort4 o; o.x = f2bf(v.x); o.y = f2bf(v.y); o.z = f2bf(v.z); o.w = f2bf(v.w);
  reinterpret_cast<ushort4*>(out)[i] = o;
}

// ---------------- tiled GEMM, BK=64, swizzled LDS (r16-verified geometry) --------------------
// MODE 0: QKV gemm, BM=128 x BN=128, grid 1152; head-packed Q/K [bh][n][64] (Q pre-scaled
// by c1), V^T [bh][64][n]. MODE 1: proj gemm, BM=64, grid 768, fp32 out + bias.
// 1D grid + T1 XCD-chunked bijective swizzle.
template<int MODE>
__global__ __launch_bounds__(256) void gemm128(
    const unsigned short* __restrict__ A, const unsigned short* __restrict__ B,
    int K, int N,
    unsigned short* __restrict__ Qh, unsigned short* __restrict__ Kh,
    unsigned short* __restrict__ Vt,
    float* __restrict__ Cf, const float* __restrict__ bias) {
  constexpr int BM = (MODE == 0) ? 128 : 64;
  constexpr int MREP = BM / 32;
  constexpr int NX = (MODE == 0) ? 18 : 6;     // blocks along N
  constexpr int CPX = (MODE == 0) ? 144 : 96;  // blocks per XCD chunk (nwg/8)
  __shared__ unsigned short Ab[BM * 64];
  __shared__ unsigned short Bb[128 * 64];
  const int tid = threadIdx.x, lane = tid & 63, wave = tid >> 6;
  const int l15 = lane & 15, lhi = lane >> 4;
  const int bid = blockIdx.x;
  const int s = (bid & 7) * CPX + (bid >> 3);  // bijective XCD-chunked remap
  const int m0 = (s / NX) * BM, n0 = (s % NX) * 128;
  const int wr = wave >> 1, wc = wave & 1;

  f32x4 acc[MREP][4] = {};

  const int srow = tid >> 3;
  const int scol = (((tid & 7) * 16) ^ ((srow & 7) << 4)) >> 1;
  const unsigned short* aSrc = A + (size_t)(m0 + srow) * K + scol;
  const unsigned short* bSrc = B + (size_t)(n0 + srow) * K + scol;
  char* ldsA = (char*)Ab + wave * 1024;
  char* ldsB = (char*)Bb + wave * 1024;

  const int rswz = (l15 & 7) << 4;

  for (int k0 = 0; k0 < K; k0 += 64) {
    __syncthreads();
#pragma unroll
    for (int i = 0; i < BM / 32; ++i)
      gload16(aSrc + k0 + (size_t)32 * K * i, ldsA + i * 4096);
#pragma unroll
    for (int i = 0; i < 4; ++i)
      gload16(bSrc + k0 + (size_t)32 * K * i, ldsB + i * 4096);
    __syncthreads();
#pragma unroll
    for (int ks = 0; ks < 2; ++ks) {
      bf16x8 af[MREP], bfr[4];
#pragma unroll
      for (int mm = 0; mm < MREP; ++mm)
        af[mm] = *reinterpret_cast<const bf16x8*>(
            (char*)Ab + (wr * (BM / 2) + mm * 16 + l15) * 128 + ((ks * 64 + lhi * 16) ^ rswz));
#pragma unroll
      for (int nn = 0; nn < 4; ++nn)
        bfr[nn] = *reinterpret_cast<const bf16x8*>(
            (char*)Bb + (wc * 64 + nn * 16 + l15) * 128 + ((ks * 64 + lhi * 16) ^ rswz));
#pragma unroll
      for (int mm = 0; mm < MREP; ++mm)
#pragma unroll
        for (int nn = 0; nn < 4; ++nn)
          acc[mm][nn] = __builtin_amdgcn_mfma_f32_16x16x32_bf16(af[mm], bfr[nn], acc[mm][nn], 0, 0, 0);
    }
  }

  if (MODE == 0) {
    const int region = (n0 >= 1536) ? 2 : (n0 >= 768 ? 1 : 0);
    const float qs = (region == 0) ? 0.125f * 1.44269504088896340736f : 1.f;
#pragma unroll
    for (int mm = 0; mm < MREP; ++mm) {
      int gm = m0 + wr * (BM / 2) + mm * 16 + lhi * 4;
      int bb = gm >> 10, nb = gm & 1023;
#pragma unroll
      for (int nn = 0; nn < 4; ++nn) {
        int gn = n0 + wc * 64 + nn * 16 + l15 - region * 768;
        int d = gn & 63, hh = gn >> 6;
        if (region == 2) {
          ushort4 o;
          o.x = f2bf(acc[mm][nn][0]); o.y = f2bf(acc[mm][nn][1]);
          o.z = f2bf(acc[mm][nn][2]); o.w = f2bf(acc[mm][nn][3]);
          *reinterpret_cast<ushort4*>(&Vt[((size_t)(bb * 12 + hh) * 64 + d) * 1024 + nb]) = o;
        } else {
          unsigned short* dst =
              (region == 0 ? Qh : Kh) + ((size_t)(bb * 12 + hh) * 1024 + nb) * 64 + d;
#pragma unroll
          for (int r = 0; r < 4; ++r) dst[(size_t)r * 64] = f2bf(acc[mm][nn][r] * qs);
        }
      }
    }
  } else {
#pragma unroll
    for (int mm = 0; mm < MREP; ++mm) {
      int gm = m0 + wr * (BM / 2) + mm * 16 + lhi * 4;
#pragma unroll
      for (int nn = 0; nn < 4; ++nn) {
        int gn = n0 + wc * 64 + nn * 16 + l15;
        float bv = bias[gn];
#pragma unroll
        for (int r = 0; r < 4; ++r)
          Cf[(size_t)(gm + r) * N + gn] = acc[mm][nn][r] + bv;
      }
    }
  }
}

// ---------------- flash attention: T15 pipeline + 2-buffer split-K/V staging -----------------
// Per iter kt: PV reads VT[kt&1], QK(kt+1) reads KT[(kt+1)&1].
// K[kt+2] staged at iter top into KT[kt&1] (dead since QK(kt) last iter, barrier1-protected);
// V[kt+2] staged after barrier2 into VT[kt&1] (PV(kt) done). Issue order K-top/V-end makes
// the top-of-iter queue [V(kt) 2, K(kt+1) 2, V(kt+1) 2]: vmcnt(2) retires exactly what this
// iter needs, leaving V[kt+1] in flight. K gets 1 iter, V ~1.3 iters of latency cover.
// LDS 32 KB -> 5 blocks/CU (vs 3 at 48 KB).
__global__ __launch_bounds__(256) void attn_kernel(
    const unsigned short* __restrict__ qh, const unsigned short* __restrict__ kh,
    const unsigned short* __restrict__ vt, unsigned short* __restrict__ aout) {
  __shared__ unsigned short KT[2][4096];  // [kv 64][d 64] swizzled, 8KB/buf
  __shared__ unsigned short VT[2][4096];  // [d 64][kv 64] swizzled, 8KB/buf

  const int tid = threadIdx.x, lane = tid & 63, wave = tid >> 6;
  const int l31 = lane & 31, hi = lane >> 5;
  // XCD-locality: all 8 q-tiles of one bh on one XCD (96 % 8 == 0)
  const int bh = blockIdx.x % 96, qt = blockIdx.x / 96;
  const int b = bh / 12, h = bh % 12;

  // staging: thread t -> tile row t>>3 (+32), chunk t&7, inverse-swizzled src col
  const int srow = tid >> 3;
  const int scol = (((tid & 7) * 16) ^ ((srow & 7) << 4)) >> 1;
  const unsigned short* kS0 = kh + ((size_t)bh * 1024 + srow) * 64 + scol;
  const unsigned short* kS1 = kS0 + (size_t)32 * 64;
  const unsigned short* vS0 = vt + ((size_t)bh * 64 + srow) * 1024 + scol;
  const unsigned short* vS1 = vS0 + (size_t)32 * 1024;
  char* kDb = (char*)&KT[0][0] + wave * 1024;
  char* vDb = (char*)&VT[0][0] + wave * 1024;

  auto stageK = [&](int kt2, int buf) {
    const int kv = kt2 * 64;
    char* kd = kDb + buf * 8192;
    gload16(kS0 + (size_t)kv * 64, kd);
    gload16(kS1 + (size_t)kv * 64, kd + 4096);
  };
  auto stageV = [&](int kt2, int buf) {
    const int kv = kt2 * 64;
    char* vd = vDb + buf * 8192;
    gload16(vS0 + kv, vd);
    gload16(vS1 + kv, vd + 4096);
  };

  // Q as B-operand (col=q=l31, k=hi*8+j), 4 k-slices of 16
  const int qw0 = qt * 128 + wave * 32;
  const unsigned short* qbase = qh + ((size_t)bh * 1024 + qw0 + l31) * 64 + hi * 8;
  bf16x8 qf[4];
#pragma unroll
  for (int ks = 0; ks < 4; ++ks)
    qf[ks] = *reinterpret_cast<const bf16x8*>(qbase + ks * 16);

  f32x16 oacc[2] = {};
  float lsum = 0.f;

  const int swz = (l31 & 7) << 4;
  const int rowb = l31 * 128;

  // PV B-frag from 8 exp'd values (verified r12-r20)
  auto mkfrag = [&](const f32x16& e, int s8) -> bf16x8 {
    unsigned A0 = cvtpk(e[s8 + 0], e[s8 + 1]);
    unsigned A1 = cvtpk(e[s8 + 2], e[s8 + 3]);
    unsigned B0 = cvtpk(e[s8 + 4], e[s8 + 5]);
    unsigned B1 = cvtpk(e[s8 + 6], e[s8 + 7]);
    plswap(A0, B0);
    plswap(A1, B1);
    union { unsigned u[4]; bf16x8 v; } wu;
    wu.u[0] = A0; wu.u[1] = A1; wu.u[2] = B0; wu.u[3] = B1;
    return wu.v;
  };

  auto qkt = [&](const char* kb, f32x16& r0, f32x16& r1) {
    __builtin_amdgcn_s_setprio(1);
#pragma unroll
    for (int ks = 0; ks < 4; ++ks) {
      bf16x8 k0 = *reinterpret_cast<const bf16x8*>(kb + rowb + ((ks * 32 + hi * 16) ^ swz));
      bf16x8 k1 = *reinterpret_cast<const bf16x8*>(kb + 4096 + rowb + ((ks * 32 + hi * 16) ^ swz));
      r0 = __builtin_amdgcn_mfma_f32_32x32x16_bf16(k0, qf[ks], r0, 0, 0, 0);
      r1 = __builtin_amdgcn_mfma_f32_32x32x16_bf16(k1, qf[ks], r1, 0, 0, 0);
    }
    __builtin_amdgcn_s_setprio(0);
  };

  // prologue: issue K0,V0,K1,V1 (that order); vmcnt(6) retires K0 only; QK(0)
  stageK(0, 0); stageV(0, 0);
  stageK(1, 1); stageV(1, 1);
  asm volatile("s_waitcnt vmcnt(6)" ::: "memory");
  __builtin_amdgcn_s_barrier();
  f32x16 pn0 = {}, pn1 = {};
  qkt((const char*)&KT[0][0], pn0, pn1);

  for (int kt = 0; kt < 16; ++kt) {
    const int cur = kt & 1;
    // retire V[kt] + K[kt+1]; keep V[kt+1] in flight (see header comment)
    if (kt < 15) {
      asm volatile("s_waitcnt vmcnt(2)" ::: "memory");
    } else {
      asm volatile("s_waitcnt vmcnt(0)" ::: "memory");
    }
    __builtin_amdgcn_s_barrier();

    // K-stage kt+2 into KT[cur] (dead; all waves past barrier1)
    if (kt + 2 <= 15) stageK(kt + 2, cur);

    // take current P from pipeline; issue NEXT tile's QK^T (MFMA fills while softmax VALU runs)
    f32x16 p0 = pn0, p1 = pn1;
    if (kt < 15) {
      pn0 = f32x16{}; pn1 = f32x16{};
      qkt((const char*)&KT[(kt + 1) & 1][0], pn0, pn1);
    }

    // shift-free softmax numerator: P = exp2(S'), running sum (verified r13)
#pragma unroll
    for (int i = 0; i < 16; ++i) {
      p0[i] = __builtin_amdgcn_exp2f(p0[i]);
      p1[i] = __builtin_amdgcn_exp2f(p1[i]);
    }
    float su[8];
#pragma unroll
    for (int i = 0; i < 8; ++i)
      su[i] = (p0[i] + p0[i + 8]) + (p1[i] + p1[i + 8]);
    float s4[4];
#pragma unroll
    for (int i = 0; i < 4; ++i) s4[i] = su[i] + su[i + 4];
    lsum += (s4[0] + s4[1]) + (s4[2] + s4[3]);

    // P -> bf16 PV B-frags in-register (T12)
    bf16x8 pb[4];
    pb[0] = mkfrag(p0, 0); pb[1] = mkfrag(p0, 8);
    pb[2] = mkfrag(p1, 0); pb[3] = mkfrag(p1, 8);

    // PV swapped: O^T[d][q] += V^T x P (reads VT[cur])
    const char* vb = (const char*)&VT[cur][0];
    __builtin_amdgcn_s_setprio(1);
#pragma unroll
    for (int kseg = 0; kseg < 4; ++kseg) {
      bf16x8 v0 = *reinterpret_cast<const bf16x8*>(vb + rowb + ((kseg * 32 + hi * 16) ^ swz));
      bf16x8 v1 = *reinterpret_cast<const bf16x8*>(vb + 4096 + rowb + ((kseg * 32 + hi * 16) ^ swz));
      oacc[0] = __builtin_amdgcn_mfma_f32_32x32x16_bf16(v0, pb[kseg], oacc[0], 0, 0, 0);
      oacc[1] = __builtin_amdgcn_mfma_f32_32x32x16_bf16(v1, pb[kseg], oacc[1], 0, 0, 0);
    }
    __builtin_amdgcn_s_setprio(0);

    // barrier2: all PV(kt) reads of VT[cur] done -> V-stage kt+2 into VT[cur]
    __builtin_amdgcn_s_barrier();
    if (kt + 2 <= 15) stageV(kt + 2, cur);
  }

  // epilogue: combine halves, normalize, write
  lsum += __shfl_xor(lsum, 32, 64);
  float inv = 1.f / lsum;
#pragma unroll
  for (int dblk = 0; dblk < 2; ++dblk)
#pragma unroll
    for (int g = 0; g < 4; ++g) {
      ushort4 o;
      o.x = f2bf(oacc[dblk][4 * g + 0] * inv);
      o.y = f2bf(oacc[dblk][4 * g + 1] * inv);
      o.z = f2bf(oacc[dblk][4 * g + 2] * inv);
      o.w = f2bf(oacc[dblk][4 * g + 3] * inv);
      int d = dblk * 32 + 8 * g + 4 * hi;  // row=(reg&3)+8*(reg>>2)+4*hi (m74)
      *reinterpret_cast<ushort4*>(
          aout + ((size_t)(b * 1024 + qw0 + l31)) * 768 + h * 64 + d) = o;
    }
}

extern "C" void kernel_launch(void* const* d_in, const int* in_sizes, int n_in,
                              void* d_out, int out_size, void* d_ws, size_t ws_size,
                              hipStream_t stream) {
  const float* x      = (const float*)d_in[0];
  const float* qkv_w  = (const float*)d_in[1];
  const float* proj_w = (const float*)d_in[2];
  const float* proj_b = (const float*)d_in[3];
  float* out = (float*)d_out;

  char* ws = (char*)d_ws;
  unsigned short* xb     = (unsigned short*)(ws);              // 8192x768 bf16
  unsigned short* wqkvb  = (unsigned short*)(ws + 12582912);   // 2304x768
  unsigned short* wprojb = (unsigned short*)(ws + 16121856);   // 768x768
  unsigned short* qhb    = (unsigned short*)(ws + 17301504);   // [96][1024][64]
  unsigned short* khb    = (unsigned short*)(ws + 29884416);   // [96][1024][64]
  unsigned short* vtb    = (unsigned short*)(ws + 42467328);   // [96][64][1024]
  unsigned short* aob    = (unsigned short*)(ws + 55050240);   // 8192x768

  cast_all<<<8448, 256, 0, stream>>>(x, qkv_w, proj_w, xb, wqkvb, wprojb);

  gemm128<0><<<1152, 256, 0, stream>>>(xb, wqkvb, 768, 2304, qhb, khb, vtb, nullptr, nullptr);

  attn_kernel<<<96 * 8, 256, 0, stream>>>(qhb, khb, vtb, aob);

  gemm128<1><<<768, 256, 0, stream>>>(aob, wprojb, 768, 768, nullptr, nullptr, nullptr, out, proj_b);
}